// Round 6
// baseline (330.072 us; speedup 1.0000x reference)
//
#include <hip/hip_runtime.h>

// Problem constants
#define VOCAB 50000
#define EMB   300
#define HID   16
#define OUTD  5
#define BSZ   128
#define SEQ   512
#define NTOK  (BSZ*SEQ)

// ws layout (in floats):
//   [0 .. 19200)     wt     : w_ih re-transposed -> [e][u][g]  (300 x 16 x 4)
//   [19200 .. 19264) bias_t : (b_ih+b_hh) permuted [u][g]
//   [19264 .. +16M)  pre    : pre-gates [tok][u][4] (i,f,g,o per unit)
//   (+ slack)        pad    : k2 prefetch overrun guard (reads only)
#define WT_OFF   0
#define BIAS_OFF 19200
#define PRE_OFF  19264

// ---------------- kernel 0: permute w_ih -> [e][u][g], fold bias ----------------
__global__ __launch_bounds__(256) void k0_prep(
    const float* __restrict__ w_ih, const float* __restrict__ b_ih,
    const float* __restrict__ b_hh, float* __restrict__ wt,
    float* __restrict__ bias_t)
{
  int i = blockIdx.x * 256 + threadIdx.x;
  if (i < 64*EMB) {
    int g = i / (16*EMB);              // gate type (i,f,g,o)
    int r = i - g * (16*EMB);
    int u = r / EMB;                   // unit
    int e = r - u * EMB;               // emb col
    wt[e * 64 + u * 4 + g] = w_ih[i];  // coalesced read
  }
  if (i < 64) {
    int u = i >> 2, g = i & 3;
    bias_t[i] = b_ih[g*16+u] + b_hh[g*16+u];
  }
}

// ---------------- kernel 1: gather + input GEMM (LDS-staged weights) ----------------
// 512 blocks x 256 threads, 2 tokens per lane. All 76.8KB of permuted weights
// live in LDS; the inner loop reads them via uniform-address ds_read_b128
// (conflict-free broadcast, NO TA/L1 cost). Round-4 evidence: k1 time scaled
// with weight VMEM instruction count -> eliminate weight VMEM entirely.
__global__ __launch_bounds__(256) void k1_pregates(
    const int* __restrict__ x, const float* __restrict__ emb,
    const float* __restrict__ wt, const float* __restrict__ bias_t,
    float* __restrict__ pre)
{
  __shared__ float4 wlds[EMB*16];       // [300][16] float4 (unit-major, gate in vec) = 76.8KB

  const float4* __restrict__ wt4 = (const float4*)wt;
  for (int i = threadIdx.x; i < EMB*16; i += 256)   // coalesced 4KB/iter
    wlds[i] = wt4[i];

  const int q    = threadIdx.x >> 6;          // unit quarter 0..3
  const int lane = threadIdx.x & 63;
  const int t0   = blockIdx.x * 128 + lane;   // token 0
  const int t1   = t0 + 64;                   // token 1

  const int r0 = x[t0];
  const int r1 = x[t1];
  const float4* __restrict__ e0 = (const float4*)(emb + (size_t)r0 * EMB);
  const float4* __restrict__ e1 = (const float4*)(emb + (size_t)r1 * EMB);

  __syncthreads();

  const float4* __restrict__ wq = &wlds[q * 4];   // wave-uniform LDS base

  float4 a0[4], a1[4];
  #pragma unroll
  for (int j = 0; j < 4; ++j) { a0[j] = make_float4(0,0,0,0); a1[j] = make_float4(0,0,0,0); }

  for (int e4 = 0; e4 < EMB/4; ++e4) {   // 75 iters
    float4 v0 = e0[e4];                  // per-lane gather (16B)
    float4 v1 = e1[e4];
    #pragma unroll
    for (int ee = 0; ee < 4; ++ee) {
      const float4* wr = wq + (size_t)(e4*4 + ee) * 16;  // uniform -> ds broadcast
      float4 w0 = wr[0], w1 = wr[1], w2 = wr[2], w3 = wr[3];
      float s0 = (ee==0) ? v0.x : (ee==1) ? v0.y : (ee==2) ? v0.z : v0.w;
      float s1 = (ee==0) ? v1.x : (ee==1) ? v1.y : (ee==2) ? v1.z : v1.w;
      a0[0].x = fmaf(s0, w0.x, a0[0].x); a0[0].y = fmaf(s0, w0.y, a0[0].y);
      a0[0].z = fmaf(s0, w0.z, a0[0].z); a0[0].w = fmaf(s0, w0.w, a0[0].w);
      a0[1].x = fmaf(s0, w1.x, a0[1].x); a0[1].y = fmaf(s0, w1.y, a0[1].y);
      a0[1].z = fmaf(s0, w1.z, a0[1].z); a0[1].w = fmaf(s0, w1.w, a0[1].w);
      a0[2].x = fmaf(s0, w2.x, a0[2].x); a0[2].y = fmaf(s0, w2.y, a0[2].y);
      a0[2].z = fmaf(s0, w2.z, a0[2].z); a0[2].w = fmaf(s0, w2.w, a0[2].w);
      a0[3].x = fmaf(s0, w3.x, a0[3].x); a0[3].y = fmaf(s0, w3.y, a0[3].y);
      a0[3].z = fmaf(s0, w3.z, a0[3].z); a0[3].w = fmaf(s0, w3.w, a0[3].w);
      a1[0].x = fmaf(s1, w0.x, a1[0].x); a1[0].y = fmaf(s1, w0.y, a1[0].y);
      a1[0].z = fmaf(s1, w0.z, a1[0].z); a1[0].w = fmaf(s1, w0.w, a1[0].w);
      a1[1].x = fmaf(s1, w1.x, a1[1].x); a1[1].y = fmaf(s1, w1.y, a1[1].y);
      a1[1].z = fmaf(s1, w1.z, a1[1].z); a1[1].w = fmaf(s1, w1.w, a1[1].w);
      a1[2].x = fmaf(s1, w2.x, a1[2].x); a1[2].y = fmaf(s1, w2.y, a1[2].y);
      a1[2].z = fmaf(s1, w2.z, a1[2].z); a1[2].w = fmaf(s1, w2.w, a1[2].w);
      a1[3].x = fmaf(s1, w3.x, a1[3].x); a1[3].y = fmaf(s1, w3.y, a1[3].y);
      a1[3].z = fmaf(s1, w3.z, a1[3].z); a1[3].w = fmaf(s1, w3.w, a1[3].w);
    }
  }

  const float4* __restrict__ bias4 = (const float4*)bias_t;  // [16] float4
  float4* __restrict__ pre4 = (float4*)pre;
  #pragma unroll
  for (int j = 0; j < 4; ++j) {
    float4 bb = bias4[q*4 + j];
    a0[j].x += bb.x; a0[j].y += bb.y; a0[j].z += bb.z; a0[j].w += bb.w;
    a1[j].x += bb.x; a1[j].y += bb.y; a1[j].z += bb.z; a1[j].w += bb.w;
    pre4[(size_t)t0 * 16 + q*4 + j] = a0[j];
    pre4[(size_t)t1 * 16 + q*4 + j] = a1[j];
  }
}

// ---------------- kernel 2: recurrence + pooling + linear ----------------
// Fast activations: raw v_exp_f32 / v_rcp_f32 (no fp32 division sequences).
__device__ __forceinline__ float sig_fast(float x) {
  return __builtin_amdgcn_rcpf(1.f + __builtin_amdgcn_exp2f(-1.44269504f * x));
}
__device__ __forceinline__ float tanh_fast2(float x) {
  return fmaf(-2.f, __builtin_amdgcn_rcpf(1.f + __builtin_amdgcn_exp2f(2.88539008f * x)), 1.f);
}

// h broadcast within each 16-lane batch row via ds_swizzle BitMode:
// new_lane = (lane & 0x10) | K within each 32-lane half -> every lane of a
// row reads h from row-lane K. No LDS write->read round trip, no barriers.
#define GETH(K) hh[K] = __int_as_float(__builtin_amdgcn_ds_swizzle(__float_as_int(h), ((K)<<5)|0x10))

// 32 blocks x 64 threads: one wave handles 4 batches x 16 units.
__global__ __launch_bounds__(64) void k2_lstm(
    const int* __restrict__ lengths,
    const float* __restrict__ w_hh,
    const float* __restrict__ w_lin,
    const float* __restrict__ b_lin,
    const float* __restrict__ pre,
    float* __restrict__ out)
{
  const int tid = threadIdx.x;
  const int u  = tid & 15;        // hidden unit
  const int bl = tid >> 4;        // local batch (0..3)
  const int b  = blockIdx.x * 4 + bl;

  // preload w_hh rows u, 16+u, 32+u, 48+u into registers (64 floats)
  const float4* __restrict__ wh4 = (const float4*)w_hh;
  float wi[16], wf[16], wg[16], wo[16];
  #pragma unroll
  for (int qq = 0; qq < 4; ++qq) {
    float4 t;
    t = wh4[(0*HID+u)*4+qq]; wi[4*qq]=t.x; wi[4*qq+1]=t.y; wi[4*qq+2]=t.z; wi[4*qq+3]=t.w;
    t = wh4[(1*HID+u)*4+qq]; wf[4*qq]=t.x; wf[4*qq+1]=t.y; wf[4*qq+2]=t.z; wf[4*qq+3]=t.w;
    t = wh4[(2*HID+u)*4+qq]; wg[4*qq]=t.x; wg[4*qq+1]=t.y; wg[4*qq+2]=t.z; wg[4*qq+3]=t.w;
    t = wh4[(3*HID+u)*4+qq]; wo[4*qq]=t.x; wo[4*qq+1]=t.y; wo[4*qq+2]=t.z; wo[4*qq+3]=t.w;
  }

  int L = lengths[b];
  L = (L < 1) ? 1 : (L > SEQ ? SEQ : L);

  // wave-level max length (4 batches in this wave) for early exit
  int Lw = L;
  Lw = max(Lw, __shfl_xor(Lw, 16, 64));
  Lw = max(Lw, __shfl_xor(Lw, 32, 64));

  const float4* __restrict__ pp = (const float4*)pre + (size_t)b * SEQ * 16 + u;

  float h = 0.f, c = 0.f;
  float s_sum = 0.f, s_max = -3.4e38f, s_last = 0.f;

  // software pipeline: 8-deep prefetch
  float4 buf[8];
  #pragma unroll
  for (int p = 0; p < 8; ++p) buf[p] = pp[(size_t)p * 16];

  for (int g = 0; g < SEQ/8; ++g) {
    if (g * 8 >= Lw) break;    // wave-uniform early exit
    #pragma unroll
    for (int p = 0; p < 8; ++p) {
      float4 cur = buf[p];
      buf[p] = pp[((size_t)(g+1)*8 + p) * 16];   // prefetch (ws slack covers overrun)
      const int s = g*8 + p;

      // all-gather h within the 16-lane row: 16 independent ds_swizzle ops
      float hh[16];
      GETH(0);  GETH(1);  GETH(2);  GETH(3);
      GETH(4);  GETH(5);  GETH(6);  GETH(7);
      GETH(8);  GETH(9);  GETH(10); GETH(11);
      GETH(12); GETH(13); GETH(14); GETH(15);

      float gi = cur.x, gf = cur.y, gg = cur.z, go = cur.w;
      #pragma unroll
      for (int k = 0; k < 16; ++k) {
        gi = fmaf(wi[k], hh[k], gi);
        gf = fmaf(wf[k], hh[k], gf);
        gg = fmaf(wg[k], hh[k], gg);
        go = fmaf(wo[k], hh[k], go);
      }
      gi = sig_fast(gi);
      gf = sig_fast(gf);
      gg = tanh_fast2(gg);
      go = sig_fast(go);
      c = fmaf(gf, c, gi * gg);
      h = go * tanh_fast2(c);

      bool act = (s < L);
      s_sum  += act ? h : 0.f;
      s_max   = act ? fmaxf(s_max, h) : s_max;
      s_last  = (s == L - 1) ? h : s_last;
    }
  }

  // stage rep = [last(16) | sum(16) | max(16)] per batch, then 48->5 linear
  __shared__ float rep[4][48];
  rep[bl][u]      = s_last;
  rep[bl][16 + u] = s_sum;
  rep[bl][32 + u] = s_max;
  __syncthreads();

  if (tid < 4 * OUTD) {
    int bo = tid / OUTD;       // local batch
    int o  = tid % OUTD;       // output idx
    float acc = b_lin[o];
    #pragma unroll
    for (int k = 0; k < 48; ++k)
      acc = fmaf(rep[bo][k], w_lin[o * 48 + k], acc);
    out[(blockIdx.x * 4 + bo) * OUTD + o] = acc;
  }
}

// ---------------- launcher ----------------
extern "C" void kernel_launch(void* const* d_in, const int* in_sizes, int n_in,
                              void* d_out, int out_size, void* d_ws, size_t ws_size,
                              hipStream_t stream)
{
  const int*   x      = (const int*)d_in[0];
  const int*   lens   = (const int*)d_in[1];
  const float* emb    = (const float*)d_in[2];
  const float* w_ih   = (const float*)d_in[3];
  const float* w_hh   = (const float*)d_in[4];
  const float* b_ih   = (const float*)d_in[5];
  const float* b_hh   = (const float*)d_in[6];
  const float* w_lin  = (const float*)d_in[7];
  const float* b_lin  = (const float*)d_in[8];
  float* out = (float*)d_out;

  float* ws     = (float*)d_ws;
  float* wt     = ws + WT_OFF;
  float* bias_t = ws + BIAS_OFF;
  float* pre    = ws + PRE_OFF;

  hipLaunchKernelGGL(k0_prep,     dim3(75),  dim3(256), 0, stream, w_ih, b_ih, b_hh, wt, bias_t);
  hipLaunchKernelGGL(k1_pregates, dim3(512), dim3(256), 0, stream, x, emb, wt, bias_t, pre);
  hipLaunchKernelGGL(k2_lstm,     dim3(32),  dim3(64),  0, stream, lens, w_hh, w_lin, b_lin, pre, out);
}

// Round 9
// 273.310 us; speedup vs baseline: 1.2077x; 1.2077x over previous
//
#include <hip/hip_runtime.h>

// Problem constants
#define VOCAB 50000
#define EMB   300
#define HID   16
#define OUTD  5
#define BSZ   128
#define SEQ   512
#define NTOK  (BSZ*SEQ)

// ws layout (in floats):
//   [0 .. 19200)     wt     : w_ih re-transposed -> [e][u][g]  (300 x 16 x 4)
//   [19200 .. 19264) bias_t : (b_ih+b_hh) permuted [u][g]
//   [19264 .. +16M)  pre    : pre-gates [tok][u][4] (i,f,g,o per unit)
//   (+ slack)        pad    : k2 prefetch overrun guard (reads only)
#define WT_OFF   0
#define BIAS_OFF 19200
#define PRE_OFF  19264

typedef float f32x2 __attribute__((ext_vector_type(2)));

// ---------------- kernel 0: permute w_ih -> [e][u][g], fold bias ----------------
__global__ __launch_bounds__(256) void k0_prep(
    const float* __restrict__ w_ih, const float* __restrict__ b_ih,
    const float* __restrict__ b_hh, float* __restrict__ wt,
    float* __restrict__ bias_t)
{
  int i = blockIdx.x * 256 + threadIdx.x;
  if (i < 64*EMB) {
    int g = i / (16*EMB);              // gate type (i,f,g,o)
    int r = i - g * (16*EMB);
    int u = r / EMB;                   // unit
    int e = r - u * EMB;               // emb col
    wt[e * 64 + u * 4 + g] = w_ih[i];  // coalesced read
  }
  if (i < 64) {
    int u = i >> 2, g = i & 3;
    bias_t[i] = b_ih[g*16+u] + b_hh[g*16+u];
  }
}

// ---------------- kernel 1: gather + input GEMM ----------------
// 256 blocks x 256 threads, FOUR tokens per lane. Evidence (r3->r4->r6): k1
// time tracks per-wave memory-op count (VMEM or DS alike), not the pipe.
// 4 tok/lane -> 256 FMA per 16 loads per e4-iter (16:1) -> FMA-issue bound
// (~38K cyc/wave, 1 wave/SIMD -> ~17us floor + stall slack).
__global__ __launch_bounds__(256, 1) void k1_pregates(
    const int* __restrict__ x, const float* __restrict__ emb,
    const float* __restrict__ wt, const float* __restrict__ bias_t,
    float* __restrict__ pre)
{
  __shared__ float4 wlds[EMB*16];       // [300][16] float4 (unit-major, gate in vec) = 76.8KB

  const float4* __restrict__ wt4 = (const float4*)wt;
  for (int i = threadIdx.x; i < EMB*16; i += 256)   // coalesced 4KB/iter
    wlds[i] = wt4[i];

  const int q    = threadIdx.x >> 6;          // unit quarter 0..3
  const int lane = threadIdx.x & 63;
  const int t0   = blockIdx.x * 256 + lane;   // 4 tokens: t0, +64, +128, +192

  const int r0 = x[t0];
  const int r1 = x[t0 + 64];
  const int r2 = x[t0 + 128];
  const int r3 = x[t0 + 192];
  const float4* __restrict__ e0 = (const float4*)(emb + (size_t)r0 * EMB);
  const float4* __restrict__ e1 = (const float4*)(emb + (size_t)r1 * EMB);
  const float4* __restrict__ e2 = (const float4*)(emb + (size_t)r2 * EMB);
  const float4* __restrict__ e3 = (const float4*)(emb + (size_t)r3 * EMB);

  __syncthreads();

  const float4* __restrict__ wq = &wlds[q * 4];   // wave-uniform LDS base

  float4 a0[4], a1[4], a2[4], a3[4];   // [token][unit j] accumulators (64 VGPR)
  #pragma unroll
  for (int j = 0; j < 4; ++j) {
    a0[j] = make_float4(0,0,0,0); a1[j] = make_float4(0,0,0,0);
    a2[j] = make_float4(0,0,0,0); a3[j] = make_float4(0,0,0,0);
  }

  for (int e4 = 0; e4 < EMB/4; ++e4) {   // 75 iters
    float4 v0 = e0[e4];                  // per-lane sequential-stream gathers
    float4 v1 = e1[e4];
    float4 v2 = e2[e4];
    float4 v3 = e3[e4];
    #pragma unroll
    for (int ee = 0; ee < 4; ++ee) {
      const float4* wr = wq + (size_t)(e4*4 + ee) * 16;  // uniform -> ds broadcast
      float4 w0 = wr[0], w1 = wr[1], w2 = wr[2], w3 = wr[3];
      float s0 = (ee==0) ? v0.x : (ee==1) ? v0.y : (ee==2) ? v0.z : v0.w;
      float s1 = (ee==0) ? v1.x : (ee==1) ? v1.y : (ee==2) ? v1.z : v1.w;
      float s2 = (ee==0) ? v2.x : (ee==1) ? v2.y : (ee==2) ? v2.z : v2.w;
      float s3 = (ee==0) ? v3.x : (ee==1) ? v3.y : (ee==2) ? v3.z : v3.w;
      #define ACC(A, S) \
        A[0].x = fmaf(S, w0.x, A[0].x); A[0].y = fmaf(S, w0.y, A[0].y); \
        A[0].z = fmaf(S, w0.z, A[0].z); A[0].w = fmaf(S, w0.w, A[0].w); \
        A[1].x = fmaf(S, w1.x, A[1].x); A[1].y = fmaf(S, w1.y, A[1].y); \
        A[1].z = fmaf(S, w1.z, A[1].z); A[1].w = fmaf(S, w1.w, A[1].w); \
        A[2].x = fmaf(S, w2.x, A[2].x); A[2].y = fmaf(S, w2.y, A[2].y); \
        A[2].z = fmaf(S, w2.z, A[2].z); A[2].w = fmaf(S, w2.w, A[2].w); \
        A[3].x = fmaf(S, w3.x, A[3].x); A[3].y = fmaf(S, w3.y, A[3].y); \
        A[3].z = fmaf(S, w3.z, A[3].z); A[3].w = fmaf(S, w3.w, A[3].w);
      ACC(a0, s0) ACC(a1, s1) ACC(a2, s2) ACC(a3, s3)
      #undef ACC
    }
  }

  const float4* __restrict__ bias4 = (const float4*)bias_t;  // [16] float4
  float4* __restrict__ pre4 = (float4*)pre;
  #pragma unroll
  for (int j = 0; j < 4; ++j) {
    float4 bb = bias4[q*4 + j];
    a0[j].x += bb.x; a0[j].y += bb.y; a0[j].z += bb.z; a0[j].w += bb.w;
    a1[j].x += bb.x; a1[j].y += bb.y; a1[j].z += bb.z; a1[j].w += bb.w;
    a2[j].x += bb.x; a2[j].y += bb.y; a2[j].z += bb.z; a2[j].w += bb.w;
    a3[j].x += bb.x; a3[j].y += bb.y; a3[j].z += bb.z; a3[j].w += bb.w;
    pre4[(size_t)(t0      ) * 16 + q*4 + j] = a0[j];
    pre4[(size_t)(t0 +  64) * 16 + q*4 + j] = a1[j];
    pre4[(size_t)(t0 + 128) * 16 + q*4 + j] = a2[j];
    pre4[(size_t)(t0 + 192) * 16 + q*4 + j] = a3[j];
  }
}

// ---------------- kernel 2: recurrence + pooling + linear ----------------
// Fast activations: raw v_exp_f32 / v_rcp_f32 (no fp32 division sequences).
__device__ __forceinline__ float sig_fast(float x) {
  return __builtin_amdgcn_rcpf(1.f + __builtin_amdgcn_exp2f(-1.44269504f * x));
}
__device__ __forceinline__ float tanh_fast2(float x) {
  return fmaf(-2.f, __builtin_amdgcn_rcpf(1.f + __builtin_amdgcn_exp2f(2.88539008f * x)), 1.f);
}

// 32 blocks x 64 threads: one wave handles 4 batches x 16 units.
// __launch_bounds__(64, 1): grid is 32 blocks (0.3% occupancy, grid-limited)
// so capping VGPRs for occupancy is pure loss — r6's VGPR=56 spilled the
// 64-float w_hh array to scratch every step (833 cyc/step). Allow 512.
// h-broadcast: wave-synchronous LDS round trip (in-order DS pipe, no barrier),
// 1 ds_write + 4x ds_read_b128-equivalent. Matvec as packed v_pk_fma_f32.
__global__ __launch_bounds__(64, 1) void k2_lstm(
    const int* __restrict__ lengths,
    const float* __restrict__ w_hh,
    const float* __restrict__ w_lin,
    const float* __restrict__ b_lin,
    const float* __restrict__ pre,
    float* __restrict__ out)
{
  const int tid = threadIdx.x;
  const int u  = tid & 15;        // hidden unit
  const int bl = tid >> 4;        // local batch (0..3)
  const int b  = blockIdx.x * 4 + bl;

  // preload w_hh rows u, 16+u, 32+u, 48+u as f32x2 pairs (64 floats)
  const float4* __restrict__ wh4 = (const float4*)w_hh;
  f32x2 wi2[8], wf2[8], wg2[8], wo2[8];
  #pragma unroll
  for (int qq = 0; qq < 4; ++qq) {
    float4 t; f32x2 p;
    t = wh4[(0*HID+u)*4+qq];
    p.x=t.x; p.y=t.y; wi2[2*qq]=p;  p.x=t.z; p.y=t.w; wi2[2*qq+1]=p;
    t = wh4[(1*HID+u)*4+qq];
    p.x=t.x; p.y=t.y; wf2[2*qq]=p;  p.x=t.z; p.y=t.w; wf2[2*qq+1]=p;
    t = wh4[(2*HID+u)*4+qq];
    p.x=t.x; p.y=t.y; wg2[2*qq]=p;  p.x=t.z; p.y=t.w; wg2[2*qq+1]=p;
    t = wh4[(3*HID+u)*4+qq];
    p.x=t.x; p.y=t.y; wo2[2*qq]=p;  p.x=t.z; p.y=t.w; wo2[2*qq+1]=p;
  }

  int L = lengths[b];
  L = (L < 1) ? 1 : (L > SEQ ? SEQ : L);

  // wave-level max length (4 batches in this wave) for early exit
  int Lw = L;
  Lw = max(Lw, __shfl_xor(Lw, 16, 64));
  Lw = max(Lw, __shfl_xor(Lw, 32, 64));

  const float4* __restrict__ pp = (const float4*)pre + (size_t)b * SEQ * 16 + u;

  __shared__ float hbuf[4][16];

  float h = 0.f, c = 0.f;
  float s_sum = 0.f, s_max = -3.4e38f, s_last = 0.f;

  // software pipeline: 8-deep prefetch
  float4 buf[8];
  #pragma unroll
  for (int p = 0; p < 8; ++p) buf[p] = pp[(size_t)p * 16];

  for (int g = 0; g < SEQ/8; ++g) {
    if (g * 8 >= Lw) break;    // wave-uniform early exit
    #pragma unroll
    for (int p = 0; p < 8; ++p) {
      float4 cur = buf[p];
      buf[p] = pp[((size_t)(g+1)*8 + p) * 16];   // prefetch (ws slack covers overrun)
      const int s = g*8 + p;

      // wave-synchronous h broadcast: 1 ds_write + vectorized reads
      hbuf[bl][u] = h;
      __builtin_amdgcn_wave_barrier();
      const f32x2* __restrict__ hb2 = (const f32x2*)(&hbuf[bl][0]);
      f32x2 hp[8];
      #pragma unroll
      for (int k = 0; k < 8; ++k) hp[k] = hb2[k];
      __builtin_amdgcn_wave_barrier();

      f32x2 ai, af, ag, ao;
      ai.x = cur.x; ai.y = 0.f;
      af.x = cur.y; af.y = 0.f;
      ag.x = cur.z; ag.y = 0.f;
      ao.x = cur.w; ao.y = 0.f;
      #pragma unroll
      for (int k = 0; k < 8; ++k) {
        ai = __builtin_elementwise_fma(wi2[k], hp[k], ai);
        af = __builtin_elementwise_fma(wf2[k], hp[k], af);
        ag = __builtin_elementwise_fma(wg2[k], hp[k], ag);
        ao = __builtin_elementwise_fma(wo2[k], hp[k], ao);
      }
      float gi = ai.x + ai.y;
      float gf = af.x + af.y;
      float gg = ag.x + ag.y;
      float go = ao.x + ao.y;

      gi = sig_fast(gi);
      gf = sig_fast(gf);
      gg = tanh_fast2(gg);
      go = sig_fast(go);
      c = fmaf(gf, c, gi * gg);
      h = go * tanh_fast2(c);

      bool act = (s < L);
      s_sum  += act ? h : 0.f;
      s_max   = act ? fmaxf(s_max, h) : s_max;
      s_last  = (s == L - 1) ? h : s_last;
    }
  }

  // stage rep = [last(16) | sum(16) | max(16)] per batch, then 48->5 linear
  __shared__ float rep[4][48];
  rep[bl][u]      = s_last;
  rep[bl][16 + u] = s_sum;
  rep[bl][32 + u] = s_max;
  __syncthreads();

  if (tid < 4 * OUTD) {
    int bo = tid / OUTD;       // local batch
    int o  = tid % OUTD;       // output idx
    float acc = b_lin[o];
    #pragma unroll
    for (int k = 0; k < 48; ++k)
      acc = fmaf(rep[bo][k], w_lin[o * 48 + k], acc);
    out[(blockIdx.x * 4 + bo) * OUTD + o] = acc;
  }
}

// ---------------- launcher ----------------
extern "C" void kernel_launch(void* const* d_in, const int* in_sizes, int n_in,
                              void* d_out, int out_size, void* d_ws, size_t ws_size,
                              hipStream_t stream)
{
  const int*   x      = (const int*)d_in[0];
  const int*   lens   = (const int*)d_in[1];
  const float* emb    = (const float*)d_in[2];
  const float* w_ih   = (const float*)d_in[3];
  const float* w_hh   = (const float*)d_in[4];
  const float* b_ih   = (const float*)d_in[5];
  const float* b_hh   = (const float*)d_in[6];
  const float* w_lin  = (const float*)d_in[7];
  const float* b_lin  = (const float*)d_in[8];
  float* out = (float*)d_out;

  float* ws     = (float*)d_ws;
  float* wt     = ws + WT_OFF;
  float* bias_t = ws + BIAS_OFF;
  float* pre    = ws + PRE_OFF;

  hipLaunchKernelGGL(k0_prep,     dim3(75),  dim3(256), 0, stream, w_ih, b_ih, b_hh, wt, bias_t);
  hipLaunchKernelGGL(k1_pregates, dim3(256), dim3(256), 0, stream, x, emb, wt, bias_t, pre);
  hipLaunchKernelGGL(k2_lstm,     dim3(32),  dim3(64),  0, stream, lens, w_hh, w_lin, b_lin, pre, out);
}